// Round 16
// baseline (58.737 us; speedup 1.0000x reference)
//
#include <hip/hip_runtime.h>
#include <math.h>

// TopK router via MFMA: logits = x @ W^T + b ; top-2 over E=64 ; sparse softmax.
// x: [T=16384, D=2048] f32, W: [64, 2048] f32, b: [64] f32.
// d_out: [T*64] router probs f32, then [T*2] top-k indices as f32.
//
// R16: DRAM-burst fix. R10-R15 all plateau at ~55 us with hbm_gbps ~1000
// (14% of ceiling): staging read <=128B per row per instr across 16
// scattered 8KB-strided rows -- short-burst DRAM death. Now each staging
// wave-instr reads 1KB CONTIGUOUS of ONE token row (lane L -> bytes
// L*16..+16); a block consumes its 16 rows as 8 sequential 1KB bursts
// each. regs -> cvt4 -> XOR-swizzled frag LDS (fl ^= ks: write banks
// fully spread, b128 A-reads keep the optimal consecutive-16B pattern).
// 2-barrier single-buffer loop, 8 chunks of 256k; x prefetch issued
// early (flies across write+MFMA). Numerics bit-identical to R14
// (absmax 0): same kstep sequence, same 6-product order, same
// 96-accumulate fp32 chains, f64 merges at kstep 16/32/48 boundaries,
// same ((m0+m1)+m2)+m3 + bias association.
// Spill sentinel: WRITE_SIZE ~4.2 MB.

#define RD 2048
#define RE 64
#define TB 16                    // tokens per block
#define NCH 8                    // chunks of 256 k

typedef __attribute__((ext_vector_type(8))) short bf16x8;
typedef __attribute__((ext_vector_type(4))) float f32x4;
typedef __attribute__((ext_vector_type(4))) unsigned int u32x4;
typedef __attribute__((ext_vector_type(2))) unsigned int u32x2;

__device__ __forceinline__ unsigned short f2b(float f) {  // RNE f32->bf16 bits
    unsigned int u = __float_as_uint(f);
    unsigned int r = ((u >> 16) & 1u) + 0x7fffu;
    return (unsigned short)((u + r) >> 16);
}
__device__ __forceinline__ float b2f(unsigned short h) {
    return __uint_as_float(((unsigned int)h) << 16);
}

// split 8 floats -> packed bf16 h/l/l2 (4 dwords each) -- wprep only
__device__ __forceinline__ void cvt8(const f32x4 a, const f32x4 bq,
                                     unsigned int* h, unsigned int* l,
                                     unsigned int* l2) {
    float v[8] = {a.x, a.y, a.z, a.w, bq.x, bq.y, bq.z, bq.w};
#pragma unroll
    for (int j = 0; j < 4; ++j) {
        const float a0 = v[2 * j], a1 = v[2 * j + 1];
        const unsigned short h0 = f2b(a0); const float r0 = a0 - b2f(h0);
        const unsigned short h1 = f2b(a1); const float r1 = a1 - b2f(h1);
        const unsigned short m0 = f2b(r0); const float s0 = r0 - b2f(m0);
        const unsigned short m1 = f2b(r1); const float s1 = r1 - b2f(m1);
        const unsigned short q0 = f2b(s0);
        const unsigned short q1 = f2b(s1);
        h[j]  = (unsigned int)h0 | ((unsigned int)h1 << 16);
        l[j]  = (unsigned int)m0 | ((unsigned int)m1 << 16);
        l2[j] = (unsigned int)q0 | ((unsigned int)q1 << 16);
    }
}

// split 4 consecutive floats -> packed bf16 h/l/l2 (2 dwords each)
__device__ __forceinline__ void cvt4(const f32x4 a,
                                     unsigned int* h, unsigned int* l,
                                     unsigned int* l2) {
    float v[4] = {a.x, a.y, a.z, a.w};
#pragma unroll
    for (int j = 0; j < 2; ++j) {
        const float a0 = v[2 * j], a1 = v[2 * j + 1];
        const unsigned short h0 = f2b(a0); const float r0 = a0 - b2f(h0);
        const unsigned short h1 = f2b(a1); const float r1 = a1 - b2f(h1);
        const unsigned short m0 = f2b(r0); const float s0 = r0 - b2f(m0);
        const unsigned short m1 = f2b(r1); const float s1 = r1 - b2f(m1);
        const unsigned short q0 = f2b(s0);
        const unsigned short q1 = f2b(s1);
        h[j]  = (unsigned int)h0 | ((unsigned int)h1 << 16);
        l[j]  = (unsigned int)m0 | ((unsigned int)m1 << 16);
        l2[j] = (unsigned int)q0 | ((unsigned int)q1 << 16);
    }
}

// ---------- prep: W -> 3-way bf16 B-fragments (identical to R10-R15) ----------
// WB dword layout: ((ks*4 + et)*3 + comp)*256 + lane*4   (64 ks total)
__global__ __launch_bounds__(256) void wprep_kernel(
    const float* __restrict__ W, unsigned int* __restrict__ WB)
{
    const int ks = blockIdx.x;            // 0..63
    const int et = threadIdx.x >> 6;      // 0..3
    const int lane = threadIdx.x & 63;
    const int e = et * 16 + (lane & 15);
    const int k0 = ks * 32 + (lane >> 4) * 8;
    const float* src = W + (size_t)e * RD + k0;
    const f32x4 a = *(const f32x4*)(src);
    const f32x4 bq = *(const f32x4*)(src + 4);
    unsigned int h[4], l[4], l2[4];
    cvt8(a, bq, h, l, l2);
    unsigned int* dst = WB + (size_t)((ks * 4 + et) * 3) * 256 + lane * 4;
    *(u32x4*)(dst)       = *(u32x4*)h;
    *(u32x4*)(dst + 256) = *(u32x4*)l;
    *(u32x4*)(dst + 512) = *(u32x4*)l2;
}

// ---------- main ----------
__global__ __launch_bounds__(256, 4) void topk_router_kernel(
    const float* __restrict__ x,
    const unsigned int* __restrict__ WB,
    const float* __restrict__ b,
    float* __restrict__ out_router,
    float* __restrict__ out_idx,
    int total_tokens)
{
    const int tid = threadIdx.x;
    const int lane = tid & 63;
    const int et = __builtin_amdgcn_readfirstlane(tid >> 6);  // etile = wave 0..3
    const int tok0 = blockIdx.x * TB;

    // A-fragment LDS: [ks][comp][fl][dw] = 24 KB, stored at fl XOR ks.
    // Aliased as lg[16][66] f64 (8.4 KB) for the epilogue.
    __shared__ __align__(16) unsigned int FR[8][3][64][4];

    // staging: round rd -> token row rd*4 + et; wave instr = 1KB contiguous
    const int tmax = total_tokens - 1;
    const float* g0 = x + (size_t)min(tok0 + 0 + et, tmax) * RD + lane * 4;
    const float* g1 = x + (size_t)min(tok0 + 4 + et, tmax) * RD + lane * 4;
    const float* g2 = x + (size_t)min(tok0 + 8 + et, tmax) * RD + lane * 4;
    const float* g3 = x + (size_t)min(tok0 + 12 + et, tmax) * RD + lane * 4;

    // frag-write coords (k4 = lane*4 within the 256-k chunk)
    const int w_ks = lane >> 3;                     // kstep 0..7
    const int w_kg = (lane >> 1) & 3;               // k-group within kstep
    const int w_d0 = (lane & 1) * 2;                // dword pair start

    f32x4 acc = {0.f, 0.f, 0.f, 0.f};
    double acc64[4] = {0.0, 0.0, 0.0, 0.0};

    // prologue: load chunk 0
    f32x4 c0 = *(const f32x4*)(g0);
    f32x4 c1 = *(const f32x4*)(g1);
    f32x4 c2 = *(const f32x4*)(g2);
    f32x4 c3 = *(const f32x4*)(g3);

#pragma unroll 1
    for (int c = 0; c < NCH; ++c) {
        // issue chunk c+1's loads early (fly across write+MFMA)
        const int cn = (c + 1 < NCH) ? (c + 1) : 0;
        const f32x4 n0 = *(const f32x4*)(g0 + (size_t)cn * 256);
        const f32x4 n1 = *(const f32x4*)(g1 + (size_t)cn * 256);
        const f32x4 n2 = *(const f32x4*)(g2 + (size_t)cn * 256);
        const f32x4 n3 = *(const f32x4*)(g3 + (size_t)cn * 256);

        __syncthreads();   // all waves done reading FR of chunk c-1

        // cvt + swizzled frag store (rows et, 4+et, 8+et, 12+et)
        {
            unsigned int h_[2], l_[2], q_[2];
            int fl_;
            cvt4(c0, h_, l_, q_);
            fl_ = (w_kg * 16 + 0 + et) ^ w_ks;
            *(u32x2*)&FR[w_ks][0][fl_][w_d0] = *(u32x2*)h_;
            *(u32x2*)&FR[w_ks][1][fl_][w_d0] = *(u32x2*)l_;
            *(u32x2*)&FR[w_ks][2][fl_][w_d0] = *(u32x2*)q_;
            cvt4(c1, h_, l_, q_);
            fl_ = (w_kg * 16 + 4 + et) ^ w_ks;
            *(u32x2*)&FR[w_ks][0][fl_][w_d0] = *(u32x2*)h_;
            *(u32x2*)&FR[w_ks][1][fl_][w_d0] = *(u32x2*)l_;
            *(u32x2*)&FR[w_ks][2][fl_][w_d0] = *(u32x2*)q_;
            cvt4(c2, h_, l_, q_);
            fl_ = (w_kg * 16 + 8 + et) ^ w_ks;
            *(u32x2*)&FR[w_ks][0][fl_][w_d0] = *(u32x2*)h_;
            *(u32x2*)&FR[w_ks][1][fl_][w_d0] = *(u32x2*)l_;
            *(u32x2*)&FR[w_ks][2][fl_][w_d0] = *(u32x2*)q_;
            cvt4(c3, h_, l_, q_);
            fl_ = (w_kg * 16 + 12 + et) ^ w_ks;
            *(u32x2*)&FR[w_ks][0][fl_][w_d0] = *(u32x2*)h_;
            *(u32x2*)&FR[w_ks][1][fl_][w_d0] = *(u32x2*)l_;
            *(u32x2*)&FR[w_ks][2][fl_][w_d0] = *(u32x2*)q_;
        }
        __syncthreads();   // frags of chunk c visible

        // MFMA pass: 8 ksteps x 6 products (this wave's etile)
#pragma unroll
        for (int ks = 0; ks < 8; ++ks) {
            const bf16x8 Ah = *(const bf16x8*)&FR[ks][0][lane ^ ks][0];
            const bf16x8 Al = *(const bf16x8*)&FR[ks][1][lane ^ ks][0];
            const bf16x8 Aq = *(const bf16x8*)&FR[ks][2][lane ^ ks][0];
            const int ksg = c * 8 + ks;
            const unsigned int* wp =
                WB + (size_t)((ksg * 4 + et) * 3) * 256 + lane * 4;
            const bf16x8 Bh = *(const bf16x8*)(wp);
            const bf16x8 Bl = *(const bf16x8*)(wp + 256);
            const bf16x8 Bq = *(const bf16x8*)(wp + 512);
            acc = __builtin_amdgcn_mfma_f32_16x16x32_bf16(Ah, Bh, acc, 0, 0, 0);
            acc = __builtin_amdgcn_mfma_f32_16x16x32_bf16(Ah, Bl, acc, 0, 0, 0);
            acc = __builtin_amdgcn_mfma_f32_16x16x32_bf16(Al, Bh, acc, 0, 0, 0);
            acc = __builtin_amdgcn_mfma_f32_16x16x32_bf16(Al, Bl, acc, 0, 0, 0);
            acc = __builtin_amdgcn_mfma_f32_16x16x32_bf16(Ah, Bq, acc, 0, 0, 0);
            acc = __builtin_amdgcn_mfma_f32_16x16x32_bf16(Aq, Bh, acc, 0, 0, 0);
        }

        // f64 merge every 2 chunks = kstep 16/32/48 boundaries (== R14)
        if ((c & 1) == 1) {
            acc64[0] += (double)acc.x; acc64[1] += (double)acc.y;
            acc64[2] += (double)acc.z; acc64[3] += (double)acc.w;
            acc = (f32x4){0.f, 0.f, 0.f, 0.f};
        }

        c0 = n0; c1 = n1; c2 = n2; c3 = n3;
    }

    // ---- exchange logits (f64) through LDS (aliases FR; 8.4 KB <= 24 KB) ----
    __syncthreads();
    double* lg = (double*)&FR[0][0][0][0];   // [16 tok][66]
#pragma unroll
    for (int r = 0; r < 4; ++r) {
        const int t = (lane >> 4) * 4 + r;                // C/D row = token
        const int e = et * 16 + (lane & 15);              // C/D col = expert
        lg[(size_t)t * 66 + e] = acc64[r];
    }
    __syncthreads();

    const double bias = (double)b[lane];

    // epilogue (R5-verified): wave et handles tokens [et*4, et*4+4)
#pragma unroll 1
    for (int i = 0; i < 4; ++i) {
        const int t = et * 4 + i;
        const int token = tok0 + t;
        const double v = lg[(size_t)t * 66 + lane] + bias;

        // argmax #1 (value desc, tie -> lower lane)
        double bestv = v;
        int besti = lane;
#pragma unroll
        for (int off = 32; off > 0; off >>= 1) {
            double ov = __shfl_xor(bestv, off, 64);
            int oi = __shfl_xor(besti, off, 64);
            if (ov > bestv || (ov == bestv && oi < besti)) { bestv = ov; besti = oi; }
        }

        // argmax #2 excluding winner
        double v2 = (lane == besti) ? -INFINITY : v;
        double best2v = v2;
        int best2i = lane;
#pragma unroll
        for (int off = 32; off > 0; off >>= 1) {
            double ov = __shfl_xor(best2v, off, 64);
            int oi = __shfl_xor(best2i, off, 64);
            if (ov > best2v || (ov == best2v && oi < best2i)) { best2v = ov; best2i = oi; }
        }

        // 2-element softmax; all other experts exactly 0
        const float e2 = expf((float)(best2v - bestv));
        const float denom = 1.0f + e2;
        const float p1v = 1.0f / denom;
        const float p2v = e2 / denom;

        if (token < total_tokens) {
            float outv = 0.0f;
            if (lane == besti) outv = p1v;
            else if (lane == best2i) outv = p2v;
            out_router[(size_t)token * RE + lane] = outv;
            if (lane == 0) {
                out_idx[(size_t)token * 2 + 0] = (float)besti;
                out_idx[(size_t)token * 2 + 1] = (float)best2i;
            }
        }
    }
}

extern "C" void kernel_launch(void* const* d_in, const int* in_sizes, int n_in,
                              void* d_out, int out_size, void* d_ws, size_t ws_size,
                              hipStream_t stream) {
    const float* x = (const float*)d_in[0];
    const float* W = (const float*)d_in[1];
    const float* b = (const float*)d_in[2];

    const int E = in_sizes[2];                 // 64
    const int D = in_sizes[1] / E;             // 2048
    const int T = in_sizes[0] / D;             // 16384
    (void)E; (void)D;

    unsigned int* WB = (unsigned int*)d_ws;    // 64*4*3*1024 B = 768 KB
    float* out_router = (float*)d_out;
    float* out_idx = out_router + (size_t)T * RE;

    wprep_kernel<<<64, 256, 0, stream>>>(W, WB);

    const int grid = (T + TB - 1) / TB;        // 1024
    topk_router_kernel<<<grid, 256, 0, stream>>>(x, WB, b, out_router, out_idx, T);
}

// Round 17
// 56.261 us; speedup vs baseline: 1.0440x; 1.0440x over previous
//
#include <hip/hip_runtime.h>
#include <math.h>

// TopK router via MFMA: logits = x @ W^T + b ; top-2 over E=64 ; sparse softmax.
// x: [T=16384, D=2048] f32, W: [64, 2048] f32, b: [64] f32.
// d_out: [T*64] router probs f32, then [T*2] top-k indices as f32.
//
// R17 = R12 (55.2 us, absmax 0.0) + register double-buffered B. Evidence
// synthesis R12-R16: barriers (R14: none, still 59), occupancy (R12: 73%,
// flat), B bandwidth (R15: halved, flat), DRAM bursts (R16: 1KB, flat) are
// all dead theories; the binder is B-load L2 LATENCY exposed serially --
// each kstep loads its B triple and consumes it immediately (~250 cyc
// stall vs ~40 cyc MFMA => duty ~15% == measured MfmaUtil 12%). Fix: issue
// chunk s+1's 6 B-loads at the top of chunk s; MFMAs of s consume triples
// loaded last chunk (guaranteed resident by the barrier's vmcnt drain).
// Steady-state B stall = 0, covered by cvt+MFMA+ds span. Named regs +
// explicit rotation (rule #20). Numerics bit-identical to R12 (absmax 0).
// Spill sentinel: WRITE_SIZE ~4.2 MB; VGPR est ~90 (cap via LB(512,3)).

#define RD 2048
#define RE 64
#define TB 16                    // tokens per block
#define NST 16                   // pipeline steps (each: 64 k per khalf)

typedef __attribute__((ext_vector_type(8))) short bf16x8;
typedef __attribute__((ext_vector_type(4))) float f32x4;
typedef __attribute__((ext_vector_type(4))) unsigned int u32x4;
typedef __attribute__((ext_vector_type(2))) unsigned int u32x2;

__device__ __forceinline__ unsigned short f2b(float f) {  // RNE f32->bf16 bits
    unsigned int u = __float_as_uint(f);
    unsigned int r = ((u >> 16) & 1u) + 0x7fffu;
    return (unsigned short)((u + r) >> 16);
}
__device__ __forceinline__ float b2f(unsigned short h) {
    return __uint_as_float(((unsigned int)h) << 16);
}

// bank-quad XOR swizzle (dword units); involution, preserves 16B alignment
__device__ __forceinline__ int swz(int f) {
    return (f << 2) ^ (((f >> 3) & 7) << 2);
}

// split 8 floats -> packed bf16 h/l/l2 (4 dwords each) -- wprep only
__device__ __forceinline__ void cvt8(const f32x4 a, const f32x4 bq,
                                     unsigned int* h, unsigned int* l,
                                     unsigned int* l2) {
    float v[8] = {a.x, a.y, a.z, a.w, bq.x, bq.y, bq.z, bq.w};
#pragma unroll
    for (int j = 0; j < 4; ++j) {
        const float a0 = v[2 * j], a1 = v[2 * j + 1];
        const unsigned short h0 = f2b(a0); const float r0 = a0 - b2f(h0);
        const unsigned short h1 = f2b(a1); const float r1 = a1 - b2f(h1);
        const unsigned short m0 = f2b(r0); const float s0 = r0 - b2f(m0);
        const unsigned short m1 = f2b(r1); const float s1 = r1 - b2f(m1);
        const unsigned short q0 = f2b(s0);
        const unsigned short q1 = f2b(s1);
        h[j]  = (unsigned int)h0 | ((unsigned int)h1 << 16);
        l[j]  = (unsigned int)m0 | ((unsigned int)m1 << 16);
        l2[j] = (unsigned int)q0 | ((unsigned int)q1 << 16);
    }
}

// split 4 floats -> packed bf16 h/l/l2 (2 dwords each); same pairing as cvt8
__device__ __forceinline__ void cvt4(const f32x4 a,
                                     unsigned int* h, unsigned int* l,
                                     unsigned int* l2) {
    float v[4] = {a.x, a.y, a.z, a.w};
#pragma unroll
    for (int j = 0; j < 2; ++j) {
        const float a0 = v[2 * j], a1 = v[2 * j + 1];
        const unsigned short h0 = f2b(a0); const float r0 = a0 - b2f(h0);
        const unsigned short h1 = f2b(a1); const float r1 = a1 - b2f(h1);
        const unsigned short m0 = f2b(r0); const float s0 = r0 - b2f(m0);
        const unsigned short m1 = f2b(r1); const float s1 = r1 - b2f(m1);
        const unsigned short q0 = f2b(s0);
        const unsigned short q1 = f2b(s1);
        h[j]  = (unsigned int)h0 | ((unsigned int)h1 << 16);
        l[j]  = (unsigned int)m0 | ((unsigned int)m1 << 16);
        l2[j] = (unsigned int)q0 | ((unsigned int)q1 << 16);
    }
}

// ---------- prep: W -> 3-way bf16 B-fragments (identical to R10-R16) ----------
// WB dword layout: ((ks*4 + et)*3 + comp)*256 + lane*4   (64 ks total)
__global__ __launch_bounds__(256) void wprep_kernel(
    const float* __restrict__ W, unsigned int* __restrict__ WB)
{
    const int ks = blockIdx.x;            // 0..63
    const int et = threadIdx.x >> 6;      // 0..3
    const int lane = threadIdx.x & 63;
    const int e = et * 16 + (lane & 15);
    const int k0 = ks * 32 + (lane >> 4) * 8;
    const float* src = W + (size_t)e * RD + k0;
    const f32x4 a = *(const f32x4*)(src);
    const f32x4 bq = *(const f32x4*)(src + 4);
    unsigned int h[4], l[4], l2[4];
    cvt8(a, bq, h, l, l2);
    unsigned int* dst = WB + (size_t)((ks * 4 + et) * 3) * 256 + lane * 4;
    *(u32x4*)(dst)       = *(u32x4*)h;
    *(u32x4*)(dst + 256) = *(u32x4*)l;
    *(u32x4*)(dst + 512) = *(u32x4*)l2;
}

// ---------- main ----------
__global__ __launch_bounds__(512, 3) void topk_router_kernel(
    const float* __restrict__ x,
    const unsigned int* __restrict__ WB,
    const float* __restrict__ b,
    float* __restrict__ out_router,
    float* __restrict__ out_idx,
    int total_tokens)
{
    const int tid = threadIdx.x;
    const int lane = tid & 63;
    const int wv = __builtin_amdgcn_readfirstlane(tid >> 6);  // 0..7
    const int kh = wv >> 2;               // k-half 0..1
    const int et = wv & 3;                // etile 0..3
    const int tok0 = blockIdx.x * TB;

    // SM[buf][kh][ks][comp][256 dwords] = 24 KB. Aliased lg[2][16][66] f64.
    __shared__ __align__(16) unsigned int SM[2][2][2][3][256];

    // staging map (identical to R12): waves 0-3 stage kh0, 4-7 stage kh1
    const int s_kh = tid >> 8;            // 0..1
    const int stok = (tid >> 4) & 15;     // 0..15
    const int part = tid & 15;            // k-quad within 64-k step
    const int tmax = total_tokens - 1;
    const float* gsrc = x + (size_t)min(tok0 + stok, tmax) * RD
                          + s_kh * 1024 + part * 4;
    const int s_ks = part >> 3;
    const int s_f  = ((part >> 1) & 3) * 16 + stok;
    const int s_off = swz(s_f) + (part & 1) * 2;

    f32x4 acc = {0.f, 0.f, 0.f, 0.f};
    double acc64[4] = {0.0, 0.0, 0.0, 0.0};

    const unsigned int* wbL = WB + lane * 4;
#define BOFF(KSG) ((size_t)(((KSG) * 4 + et) * 3) * 256)

    // prologue: stage x step 0, prefetch x step 1, load B triples of step 0
    {
        const f32x4 v0 = *(const f32x4*)(gsrc);
        unsigned int h[2], l[2], l2[2];
        cvt4(v0, h, l, l2);
        *(u32x2*)&SM[0][s_kh][s_ks][0][s_off] = *(u32x2*)h;
        *(u32x2*)&SM[0][s_kh][s_ks][1][s_off] = *(u32x2*)l;
        *(u32x2*)&SM[0][s_kh][s_ks][2][s_off] = *(u32x2*)l2;
    }
    f32x4 pf = *(const f32x4*)(gsrc + 64);
    const int ksg_0 = kh * 32;
    bf16x8 Bc0h = *(const bf16x8*)(wbL + BOFF(ksg_0));
    bf16x8 Bc0l = *(const bf16x8*)(wbL + BOFF(ksg_0) + 256);
    bf16x8 Bc0q = *(const bf16x8*)(wbL + BOFF(ksg_0) + 512);
    bf16x8 Bc1h = *(const bf16x8*)(wbL + BOFF(ksg_0 + 1));
    bf16x8 Bc1l = *(const bf16x8*)(wbL + BOFF(ksg_0 + 1) + 256);
    bf16x8 Bc1q = *(const bf16x8*)(wbL + BOFF(ksg_0 + 1) + 512);
    __syncthreads();

#pragma unroll 1
    for (int s = 0; s < NST; ++s) {
        const int buf = s & 1;
        // x prefetch for step s+2 (2-deep, as in R12)
        const int cn = (s + 2 < NST) ? (s + 2) : 0;
        const f32x4 nx = *(const f32x4*)(gsrc + (size_t)cn * 64);

        // issue NEXT step's 6 B-loads now; they drain at this step's barrier
        const int nk = (s + 1 < NST) ? (s + 1) : 0;
        const int ksgn = kh * 32 + nk * 2;
        const bf16x8 Bn0h = *(const bf16x8*)(wbL + BOFF(ksgn));
        const bf16x8 Bn0l = *(const bf16x8*)(wbL + BOFF(ksgn) + 256);
        const bf16x8 Bn0q = *(const bf16x8*)(wbL + BOFF(ksgn) + 512);
        const bf16x8 Bn1h = *(const bf16x8*)(wbL + BOFF(ksgn + 1));
        const bf16x8 Bn1l = *(const bf16x8*)(wbL + BOFF(ksgn + 1) + 256);
        const bf16x8 Bn1q = *(const bf16x8*)(wbL + BOFF(ksgn + 1) + 512);

        // compute step s with CURRENT B triples (already in regs, no stall);
        // MFMA order per kstep identical to R12: hh, hl, lh, ll, hq, qh
        {
            const bf16x8 Ah = *(const bf16x8*)&SM[buf][kh][0][0][swz(lane)];
            const bf16x8 Al = *(const bf16x8*)&SM[buf][kh][0][1][swz(lane)];
            const bf16x8 Aq = *(const bf16x8*)&SM[buf][kh][0][2][swz(lane)];
            acc = __builtin_amdgcn_mfma_f32_16x16x32_bf16(Ah, Bc0h, acc, 0, 0, 0);
            acc = __builtin_amdgcn_mfma_f32_16x16x32_bf16(Ah, Bc0l, acc, 0, 0, 0);
            acc = __builtin_amdgcn_mfma_f32_16x16x32_bf16(Al, Bc0h, acc, 0, 0, 0);
            acc = __builtin_amdgcn_mfma_f32_16x16x32_bf16(Al, Bc0l, acc, 0, 0, 0);
            acc = __builtin_amdgcn_mfma_f32_16x16x32_bf16(Ah, Bc0q, acc, 0, 0, 0);
            acc = __builtin_amdgcn_mfma_f32_16x16x32_bf16(Aq, Bc0h, acc, 0, 0, 0);
        }
        {
            const bf16x8 Ah = *(const bf16x8*)&SM[buf][kh][1][0][swz(lane)];
            const bf16x8 Al = *(const bf16x8*)&SM[buf][kh][1][1][swz(lane)];
            const bf16x8 Aq = *(const bf16x8*)&SM[buf][kh][1][2][swz(lane)];
            acc = __builtin_amdgcn_mfma_f32_16x16x32_bf16(Ah, Bc1h, acc, 0, 0, 0);
            acc = __builtin_amdgcn_mfma_f32_16x16x32_bf16(Ah, Bc1l, acc, 0, 0, 0);
            acc = __builtin_amdgcn_mfma_f32_16x16x32_bf16(Al, Bc1h, acc, 0, 0, 0);
            acc = __builtin_amdgcn_mfma_f32_16x16x32_bf16(Al, Bc1l, acc, 0, 0, 0);
            acc = __builtin_amdgcn_mfma_f32_16x16x32_bf16(Ah, Bc1q, acc, 0, 0, 0);
            acc = __builtin_amdgcn_mfma_f32_16x16x32_bf16(Aq, Bc1h, acc, 0, 0, 0);
        }

        // f64 partial merge every 8 steps (boundaries identical to R12)
        if ((s & 7) == 7) {
            acc64[0] += (double)acc.x; acc64[1] += (double)acc.y;
            acc64[2] += (double)acc.z; acc64[3] += (double)acc.w;
            acc = (f32x4){0.f, 0.f, 0.f, 0.f};
        }

        // write step s+1 (prefetched last iteration) into the other buffer
        if (s + 1 < NST) {
            unsigned int h[2], l[2], l2[2];
            cvt4(pf, h, l, l2);
            const int nbuf = (s + 1) & 1;
            *(u32x2*)&SM[nbuf][s_kh][s_ks][0][s_off] = *(u32x2*)h;
            *(u32x2*)&SM[nbuf][s_kh][s_ks][1][s_off] = *(u32x2*)l;
            *(u32x2*)&SM[nbuf][s_kh][s_ks][2][s_off] = *(u32x2*)l2;
        }
        pf = nx;
        Bc0h = Bn0h; Bc0l = Bn0l; Bc0q = Bn0q;
        Bc1h = Bn1h; Bc1l = Bn1l; Bc1q = Bn1q;
        __syncthreads();
    }

    // ---- exchange logits (f64) through LDS (aliases SM) ----
    double* lg = (double*)&SM[0][0][0][0][0];   // [2 kh][16 tok][66]
#pragma unroll
    for (int r = 0; r < 4; ++r) {
        const int t = (lane >> 4) * 4 + r;                // C/D row = token
        const int e = et * 16 + (lane & 15);              // C/D col = expert
        lg[(size_t)(kh * TB + t) * 66 + e] = acc64[r];
    }
    __syncthreads();

    const double bias = (double)b[lane];

    // epilogue (R5-verified): wave wv handles tokens [wv*2, wv*2+2)
#pragma unroll 1
    for (int i = 0; i < 2; ++i) {
        const int t = wv * 2 + i;
        const int token = tok0 + t;
        const double v = lg[(size_t)t * 66 + lane]
                       + lg[(size_t)(TB + t) * 66 + lane] + bias;

        // argmax #1 (value desc, tie -> lower lane)
        double bestv = v;
        int besti = lane;
#pragma unroll
        for (int off = 32; off > 0; off >>= 1) {
            double ov = __shfl_xor(bestv, off, 64);
            int oi = __shfl_xor(besti, off, 64);
            if (ov > bestv || (ov == bestv && oi < besti)) { bestv = ov; besti = oi; }
        }

        // argmax #2 excluding winner
        double v2 = (lane == besti) ? -INFINITY : v;
        double best2v = v2;
        int best2i = lane;
#pragma unroll
        for (int off = 32; off > 0; off >>= 1) {
            double ov = __shfl_xor(best2v, off, 64);
            int oi = __shfl_xor(best2i, off, 64);
            if (ov > best2v || (ov == best2v && oi < best2i)) { best2v = ov; best2i = oi; }
        }

        // 2-element softmax; all other experts exactly 0
        const float e2 = expf((float)(best2v - bestv));
        const float denom = 1.0f + e2;
        const float p1v = 1.0f / denom;
        const float p2v = e2 / denom;

        if (token < total_tokens) {
            float outv = 0.0f;
            if (lane == besti) outv = p1v;
            else if (lane == best2i) outv = p2v;
            out_router[(size_t)token * RE + lane] = outv;
            if (lane == 0) {
                out_idx[(size_t)token * 2 + 0] = (float)besti;
                out_idx[(size_t)token * 2 + 1] = (float)best2i;
            }
        }
    }
}

extern "C" void kernel_launch(void* const* d_in, const int* in_sizes, int n_in,
                              void* d_out, int out_size, void* d_ws, size_t ws_size,
                              hipStream_t stream) {
    const float* x = (const float*)d_in[0];
    const float* W = (const float*)d_in[1];
    const float* b = (const float*)d_in[2];

    const int E = in_sizes[2];                 // 64
    const int D = in_sizes[1] / E;             // 2048
    const int T = in_sizes[0] / D;             // 16384
    (void)E; (void)D;

    unsigned int* WB = (unsigned int*)d_ws;    // 64*4*3*1024 B = 768 KB
    float* out_router = (float*)d_out;
    float* out_idx = out_router + (size_t)T * RE;

    wprep_kernel<<<64, 256, 0, stream>>>(W, WB);

    const int grid = (T + TB - 1) / TB;        // 1024
    topk_router_kernel<<<grid, 512, 0, stream>>>(x, WB, b, out_router, out_idx, T);
}